// Round 1
// baseline (663.050 us; speedup 1.0000x reference)
//
#include <hip/hip_runtime.h>
#include <math.h>

// x: [8, 64, 64, 64, 64] f32. slice per (b,c) = 64*64*64 = 262144 floats = 1 MiB.
// 512 slices. Pool window (2,2,2): out block = max8 + sum8/8, summed over slice.
// Kernel 1: 4 workgroups per slice, 256 threads each. Thread task = 2 d-blocks
// (one float4 in d) x 4 (h,w) quadrants. 16 tasks/thread.
// Kernel 2: 512 threads, 1 wg. s -> pooled=s^2 -> per-b L2 norm over c.

__global__ __launch_bounds__(256) void pool_reduce_kernel(const float* __restrict__ x,
                                                          float* __restrict__ part_out) {
    const int g = blockIdx.x;      // 0..2047
    const int bc = g >> 2;         // 0..511
    const int part = g & 3;        // 0..3
    const float* base = x + (size_t)bc * 262144;
    const int tid = threadIdx.x;

    float acc = 0.0f;
#pragma unroll
    for (int i = 0; i < 16; ++i) {
        const int t = part * 4096 + i * 256 + tid;   // task id in [0,16384)
        const int d4 = t & 15;          // 16 float4 positions along d (64 floats)
        const int w0 = (t >> 4) & 31;   // 32 w block positions
        const int h0 = t >> 9;          // 32 h block positions
        const float* p = base + h0 * 8192 + w0 * 128 + d4 * 4;
        const float4 a = *reinterpret_cast<const float4*>(p);          // (h, w  , d..d+3)
        const float4 b = *reinterpret_cast<const float4*>(p + 64);     // (h, w+1, ...)
        const float4 c = *reinterpret_cast<const float4*>(p + 4096);   // (h+1, w , ...)
        const float4 d = *reinterpret_cast<const float4*>(p + 4160);   // (h+1, w+1, ...)
        // d-block 0 uses .x/.y of each quadrant; d-block 1 uses .z/.w
        const float m0 = fmaxf(fmaxf(fmaxf(a.x, a.y), fmaxf(b.x, b.y)),
                               fmaxf(fmaxf(c.x, c.y), fmaxf(d.x, d.y)));
        const float s0 = ((a.x + a.y) + (b.x + b.y)) + ((c.x + c.y) + (d.x + d.y));
        const float m1 = fmaxf(fmaxf(fmaxf(a.z, a.w), fmaxf(b.z, b.w)),
                               fmaxf(fmaxf(c.z, c.w), fmaxf(d.z, d.w)));
        const float s1 = ((a.z + a.w) + (b.z + b.w)) + ((c.z + c.w) + (d.z + d.w));
        acc += (m0 + s0 * 0.125f) + (m1 + s1 * 0.125f);
    }

    // 64-lane wave reduce
#pragma unroll
    for (int off = 32; off; off >>= 1) acc += __shfl_xor(acc, off);

    __shared__ float lds[4];
    const int lane = tid & 63;
    const int wave = tid >> 6;
    if (lane == 0) lds[wave] = acc;
    __syncthreads();
    if (tid == 0) part_out[g] = (lds[0] + lds[1]) + (lds[2] + lds[3]);
}

__global__ __launch_bounds__(512) void finalize_kernel(const float* __restrict__ parts,
                                                       float* __restrict__ out) {
    const int j = threadIdx.x;  // 0..511 = b*64 + c; wave index == b
    const float s = (parts[4 * j] + parts[4 * j + 1]) + (parts[4 * j + 2] + parts[4 * j + 3]);
    const float pooled = s * s;
    float p2 = pooled * pooled;
#pragma unroll
    for (int off = 32; off; off >>= 1) p2 += __shfl_xor(p2, off);  // sum over the 64 c's of this b
    const float norm = fmaxf(sqrtf(p2), 1e-12f);
    out[j] = pooled / norm;
}

extern "C" void kernel_launch(void* const* d_in, const int* in_sizes, int n_in,
                              void* d_out, int out_size, void* d_ws, size_t ws_size,
                              hipStream_t stream) {
    const float* x = (const float*)d_in[0];
    float* out = (float*)d_out;
    float* parts = (float*)d_ws;  // 2048 floats

    pool_reduce_kernel<<<2048, 256, 0, stream>>>(x, parts);
    finalize_kernel<<<1, 512, 0, stream>>>(parts, out);
}